// Round 10
// baseline (320.106 us; speedup 1.0000x reference)
//
#include <hip/hip_runtime.h>
#include <math.h>

// ---------------------------------------------------------------------------
// HybridBinaryClassifier360: conv1(3->6,5x5,s2,p1)+relu+maxpool2s1 ->
// conv2(6->15,3x3,s2,p1)+relu+maxpool2s1 -> fc 55815->120->84->1 ->
// RBF kernel vs 10 supports -> sigmoid -> [p, 1-p].  B=128, fp32.
//
// R19: conv1 -> SINGLE-WAVE blocks. R11-R18 conv1 was latency-bound (VALU
// 47%, occ 28%): 8 block-wide barriers across 4 waves serialize every
// staging round, and VGPR=76 caps residency. Fix the barriers instead of
// the registers: 64-thr blocks (8 conv rows x 8 strips, 7 pooled rows/tile,
// LDS slice [19][78]=5.9KB). __syncthreads in a 1-wave block = no cross-
// wave wait; pooling partner is ALWAYS shfl_down(8) (cbuf/edge machinery
// deleted; t=7 is shfl-source only). Cost: +1/7 boundary conv row dup
// compute, staging rows overlap 5/19 (FETCH 77->~95MB, L3-resident).
// 9216 independent waves; NO launch-bounds pin (R10/R13/R16 rule).
// conv2/fc1/reduce/head byte-identical to R18.
// ---------------------------------------------------------------------------

#define BATCH 128
#define KPAD 55816              // act row stride (floats); 16B-aligned rows

// ---------------- Kernel 1: conv1 + relu + maxpool(2,s1) -------------------
// x [128,3,250,250] -> pool1 [128,6,123,123]
// block 64 = 8 rowgroups(x1 conv row) x 8 strips(x4 pooled cols);
// tile 7 pooled rows x 32 pooled cols; grid (4, 18, 128) = 9216 blocks.
// LDS slice [19][78] (69 cols used, skew il+(il>>3)) = 5928 B.
// Magic div: i/69 = (i*121575)>>23 (valid i < 125203).
#define C1_ST 78
#define C1S_ROWS 19
#define C1S_TOT (C1S_ROWS * 69)      // 1311
__global__ __launch_bounds__(64) void conv1_pool_kernel(
    const float* __restrict__ x, const float* __restrict__ w,
    const float* __restrict__ bias, float* __restrict__ out) {
  const int b = blockIdx.z;
  const int P0 = blockIdx.x * 32;    // first pooled col
  const int R0 = blockIdx.y * 7;     // first pooled row
  const int tid = threadIdx.x;
  const int t = tid >> 3;            // rowgroup 0..7 (conv row R0+t)
  const int s = tid & 7;             // strip 0..7 (4 pooled cols)

  __shared__ float lds[C1S_ROWS * C1_ST];   // 1482 floats = 5928 B

  float acc[5][6];                   // conv row R0+t x 5 conv cols x 6 oc
#pragma unroll
  for (int oc = 0; oc < 6; oc++) {
    float bv = bias[oc];
#pragma unroll
    for (int dc = 0; dc < 5; dc++) acc[dc][oc] = bv;
  }

  const int ihb = 2 * R0 - 1, iwb = 2 * P0 - 1;

#pragma unroll 1
  for (int ci = 0; ci < 3; ci++) {
    __syncthreads();                 // WAR; 1-wave block: no cross-wave wait
    const float* src = x + (size_t)(b * 3 + ci) * 62500;
#pragma unroll 1
    for (int base = tid; base < C1S_TOT; base += 256) {
      float vv[4];
      int lrv[4], ilv[4];
#pragma unroll
      for (int k = 0; k < 4; k++) {
        int i = base + (k << 6);
        int lr = (int)(((unsigned)i * 121575u) >> 23);  // i / 69
        int il = i - lr * 69;                           // i % 69
        lrv[k] = lr; ilv[k] = il;
        int ih = ihb + lr, iw = iwb + il;
        bool ok = (i < C1S_TOT) && ((unsigned)ih < 250u) && ((unsigned)iw < 250u);
        vv[k] = ok ? src[ih * 250 + iw] : 0.f;
      }
#pragma unroll
      for (int k = 0; k < 4; k++) {
        int i = base + (k << 6);
        if (i < C1S_TOT) lds[lrv[k] * C1_ST + ilv[k] + (ilv[k] >> 3)] = vv[k];
      }
    }
    __syncthreads();                 // RAW: staging visible

    // input slice rows for conv row R0+t: lr = 2t + ir, ir = 0..4 (kh)
    // col map: addr = il + (il>>3), il = 8s+j -> 9s+j (j<8), 9s+j+1 (j>=8)
    const float* rbase = &lds[(2 * t) * C1_ST + 9 * s];
#pragma unroll
    for (int ir = 0; ir < 5; ir++) {
      const float* rpl = rbase + ir * C1_ST;
      const float* rph = rpl + 1;
      float v[13];
#pragma unroll
      for (int j = 0; j < 8; j++)  v[j] = rpl[j];
#pragma unroll
      for (int j = 8; j < 13; j++) v[j] = rph[j];
#pragma unroll
      for (int oc = 0; oc < 6; oc++) {
        const float* wr = w + ((oc * 3 + ci) * 5 + ir) * 5;
        float w0 = wr[0], w1 = wr[1], w2 = wr[2], w3 = wr[3], w4 = wr[4];
#pragma unroll
        for (int dc = 0; dc < 5; dc++) {
          float a = acc[dc][oc];
          a += w0 * v[2 * dc + 0];
          a += w1 * v[2 * dc + 1];
          a += w2 * v[2 * dc + 2];
          a += w3 * v[2 * dc + 3];
          a += w4 * v[2 * dc + 4];
          acc[dc][oc] = a;
        }
      }
    }
  }

  // ---- pooled row p0 = R0+t = max(conv t [own], conv t+1 [lane+8]) ----
  // t=7 is shfl-source only (its pooled row belongs to the next tile).
  const int p0 = R0 + t;
  const int c0 = P0 + 4 * s;
  const bool wr_ok = (t < 7) && (p0 < 123);

#pragma unroll
  for (int oc = 0; oc < 6; oc++) {
    float a0 = acc[0][oc], a1 = acc[1][oc], a2 = acc[2][oc],
          a3 = acc[3][oc], a4 = acc[4][oc];
    // shuffles issued by ALL lanes (sources must be active)
    float n0 = __shfl_down(a0, 8), n1 = __shfl_down(a1, 8),
          n2 = __shfl_down(a2, 8), n3 = __shfl_down(a3, 8),
          n4 = __shfl_down(a4, 8);
    if (wr_ok) {
      float* orow = out + ((size_t)(b * 6 + oc) * 123 + p0) * 123;
      float m0 = fmaxf(fmaxf(fmaxf(a0, a1), fmaxf(n0, n1)), 0.f);
      float m1 = fmaxf(fmaxf(fmaxf(a1, a2), fmaxf(n1, n2)), 0.f);
      float m2 = fmaxf(fmaxf(fmaxf(a2, a3), fmaxf(n2, n3)), 0.f);
      float m3 = fmaxf(fmaxf(fmaxf(a3, a4), fmaxf(n3, n4)), 0.f);
      if (c0 + 3 < 123) {
        *(float4*)&orow[c0] = make_float4(m0, m1, m2, m3);
      } else {
        if (c0 < 123) orow[c0] = m0;
        if (c0 + 1 < 123) orow[c0 + 1] = m1;
        if (c0 + 2 < 123) orow[c0 + 2] = m2;
      }
    }
  }
}

// ---------------- Kernel 2: conv2 + relu + maxpool(2,s1) -------------------
// pool1 [128,6,123,123] -> act [128][KPAD] (k = oc*3721 + r*61 + c, padded)
// (EXACT R18 kernel: compute-once, shfl_down(16) partner)
#define C2_ST 84
#define C2_TOT (35 * 67)    // 2345
__global__ __launch_bounds__(256) void conv2_pool_kernel(
    const float* __restrict__ in, const float* __restrict__ w,
    const float* __restrict__ bias, float* __restrict__ out) {
  const int b = blockIdx.z;
  const int P0 = blockIdx.x * 32;
  const int R0 = blockIdx.y * 16;
  const int tid = threadIdx.x;
  const int t = tid >> 4;           // conv/pooled row 0..15
  const int s = tid & 15;           // strip 0..15 (2 pooled cols)

  __shared__ float lds[35 * C2_ST];   // 11760 B
  float* cbuf = lds;                  // exchange reuses [0,2160) after compute

  const int ihb = 2 * R0 - 1, iwb = 2 * P0 - 1;
  const int r = R0 + t;
  const int c0 = P0 + 2 * s;

  float acc0[3][15];                // conv row r x 3 conv cols x 15 oc
  float acc1[3][15];                // conv row r+1 (live only for t==15)
#pragma unroll
  for (int oc = 0; oc < 15; oc++) {
    float bv = bias[oc];
#pragma unroll
    for (int dc = 0; dc < 3; dc++) { acc0[dc][oc] = bv; acc1[dc][oc] = bv; }
  }

#pragma unroll 1
  for (int ci = 0; ci < 6; ci++) {
    __syncthreads();               // WAR
    const float* src = in + (size_t)(b * 6 + ci) * 15129;  // 123*123
#pragma unroll 1
    for (int base = tid; base < C2_TOT; base += 1024) {
      float vv[4];
      int ladr[4];
#pragma unroll
      for (int k = 0; k < 4; k++) {
        int i = base + (k << 8);
        int lr = (int)(((unsigned)i * 125204u) >> 23);  // i / 67
        int il = i - lr * 67;                           // i % 67
        int ih = ihb + lr, iw = iwb + il;
        bool ok = (i < C2_TOT) && ((unsigned)ih < 123u) && ((unsigned)iw < 123u);
        vv[k] = ok ? src[ih * 123 + iw] : 0.f;
        ladr[k] = (i < C2_TOT) ? (lr * C2_ST + il + (il >> 2)) : -1;
      }
#pragma unroll
      for (int k = 0; k < 4; k++) {
        if (ladr[k] >= 0) lds[ladr[k]] = vv[k];
      }
    }
    __syncthreads();               // RAW

    // own conv row r: kh = ir = 0..2, input rows 2t+ir
#pragma unroll 1
    for (int ir = 0; ir < 3; ir++) {
      const float* rp = &lds[(2 * t + ir) * C2_ST + 5 * s];
      float v[7];
#pragma unroll
      for (int j = 0; j < 7; j++) v[j] = rp[j + (j >> 2)];
#pragma unroll
      for (int oc = 0; oc < 15; oc++) {
        const float* wr = w + ((oc * 6 + ci) * 3 + ir) * 3;
        float w0 = wr[0], w1 = wr[1], w2 = wr[2];
#pragma unroll
        for (int dc = 0; dc < 3; dc++) {
          float a = acc0[dc][oc];
          a += w0 * v[2 * dc + 0];
          a += w1 * v[2 * dc + 1];
          a += w2 * v[2 * dc + 2];
          acc0[dc][oc] = a;
        }
      }
    }
    // block-edge row r+1 = R0+16: only t==15 (16 lanes, exec-masked)
    if (t == 15) {
#pragma unroll 1
      for (int kh = 0; kh < 3; kh++) {
        const float* rp = &lds[(32 + kh) * C2_ST + 5 * s];
        float v[7];
#pragma unroll
        for (int j = 0; j < 7; j++) v[j] = rp[j + (j >> 2)];
#pragma unroll
        for (int oc = 0; oc < 15; oc++) {
          const float* wr = w + ((oc * 6 + ci) * 3 + kh) * 3;
          float w0 = wr[0], w1 = wr[1], w2 = wr[2];
#pragma unroll
          for (int dc = 0; dc < 3; dc++) {
            float a = acc1[dc][oc];
            a += w0 * v[2 * dc + 0];
            a += w1 * v[2 * dc + 1];
            a += w2 * v[2 * dc + 2];
            acc1[dc][oc] = a;
          }
        }
      }
    }
  }

  // ---- wave-boundary exchange: t=4/8/12 publish acc0 for t=3/7/11 ----
  __syncthreads();                   // all compute done; staging LDS dead
  if (t == 4 || t == 8 || t == 12) {
    float* cb = &cbuf[(((t >> 2) - 1) * 16 + s) * 45];
#pragma unroll
    for (int oc = 0; oc < 15; oc++)
#pragma unroll
      for (int dc = 0; dc < 3; dc++) cb[oc * 3 + dc] = acc0[dc][oc];
  }
  __syncthreads();                   // cbuf visible

  const bool edge = (t == 3 || t == 7 || t == 11);
  const float* cb = &cbuf[((t >> 2) * 16 + s) * 45];
  const bool wr_ok = (r < 61);

#pragma unroll
  for (int oc = 0; oc < 15; oc++) {
    float a0 = acc0[0][oc], a1 = acc0[1][oc], a2 = acc0[2][oc];
    // shuffles issued by ALL lanes (sources must be active)
    float n0 = __shfl_down(a0, 16), n1 = __shfl_down(a1, 16),
          n2 = __shfl_down(a2, 16);
    if (edge) {
      n0 = cb[oc * 3 + 0]; n1 = cb[oc * 3 + 1]; n2 = cb[oc * 3 + 2];
    }
    if (t == 15) {
      n0 = acc1[0][oc]; n1 = acc1[1][oc]; n2 = acc1[2][oc];
    }
    if (wr_ok) {
      float* orow = out + (size_t)b * KPAD + (oc * 3721 + r * 61);
      float m0 = fmaxf(fmaxf(fmaxf(a0, a1), fmaxf(n0, n1)), 0.f);
      float m1 = fmaxf(fmaxf(fmaxf(a1, a2), fmaxf(n1, n2)), 0.f);
      if (c0 + 1 < 61) {
        *(float2*)&orow[c0] = make_float2(m0, m1);
      } else if (c0 < 61) {
        orow[c0] = m0;
      }
    }
  }
}

// ---------------- Kernel 3: fc1 split-K GEMM partials ----------------------
// (EXACT R15/R18 kernel: NPART=512, KCHUNK=112, KSTEP=16, float4 A staging)
#define KTOT 55815
#define NPART 512
#define KCHUNK 112
#define KSTEP 16
__global__ __launch_bounds__(512) void fc1_splitk_kernel(
    const float* __restrict__ act, const float* __restrict__ w,
    float* __restrict__ partial) {
  const int kbase = blockIdx.x * KCHUNK;
  const int tid = threadIdx.x;
  const int tx = tid & 31, ty = tid >> 5;
  __shared__ float ldsA[KSTEP * 132];
  __shared__ float ldsB[KSTEP * 132];
  float acc[8][4];
#pragma unroll
  for (int i = 0; i < 8; i++)
#pragma unroll
    for (int j = 0; j < 4; j++) acc[i][j] = 0.f;

  const int mA = tid >> 2;            // 0..127
  const int qA = (tid & 3) * 4;       // k offset within step: 0,4,8,12

  for (int s16 = 0; s16 < KCHUNK / KSTEP; s16++) {
    int kofs = kbase + s16 * KSTEP;
    __syncthreads();
    { // ---- A: 128 rows x 16 k = 2048 floats = 512 aligned float4 ----
      int k = kofs + qA;
      float4 a4;
      if (k + 3 < KTOT) {
        a4 = *(const float4*)&act[(size_t)mA * KPAD + k];
      } else {
        a4.x = (k + 0 < KTOT) ? act[(size_t)mA * KPAD + k + 0] : 0.f;
        a4.y = (k + 1 < KTOT) ? act[(size_t)mA * KPAD + k + 1] : 0.f;
        a4.z = (k + 2 < KTOT) ? act[(size_t)mA * KPAD + k + 2] : 0.f;
        a4.w = (k + 3 < KTOT) ? act[(size_t)mA * KPAD + k + 3] : 0.f;
      }
      ldsA[(qA + 0) * 132 + mA] = a4.x;
      ldsA[(qA + 1) * 132 + mA] = a4.y;
      ldsA[(qA + 2) * 132 + mA] = a4.z;
      ldsA[(qA + 3) * 132 + mA] = a4.w;
    }
    // ---- B: 120 rows x 16 k = 1920 floats, scalar coalesced ----
    for (int i = tid; i < 1920; i += 512) {
      int n = i >> 4, kk = i & 15;
      int k = kofs + kk;
      ldsB[kk * 132 + n] = (k < KTOT) ? w[n * KTOT + k] : 0.f;
    }
    __syncthreads();
#pragma unroll
    for (int kk = 0; kk < KSTEP; kk++) {
      float4 a0 = *(const float4*)&ldsA[kk * 132 + ty * 8];
      float4 a1 = *(const float4*)&ldsA[kk * 132 + ty * 8 + 4];
      float4 b0 = *(const float4*)&ldsB[kk * 132 + tx * 4];
      float av[8] = {a0.x, a0.y, a0.z, a0.w, a1.x, a1.y, a1.z, a1.w};
      float bv[4] = {b0.x, b0.y, b0.z, b0.w};
#pragma unroll
      for (int i = 0; i < 8; i++)
#pragma unroll
        for (int j = 0; j < 4; j++) acc[i][j] += av[i] * bv[j];
    }
  }

  if (tx < 30) {
    float* dst = partial + (size_t)blockIdx.x * 15360;
#pragma unroll
    for (int i = 0; i < 8; i++) {
      int row = ty * 8 + i;
      float4 st = make_float4(acc[i][0], acc[i][1], acc[i][2], acc[i][3]);
      *(float4*)&dst[row * 120 + tx * 4] = st;
    }
  }
}

// ---------------- Kernel 4: fused reduce (512 partials) + bias + relu ------
// (EXACT R15/R18 kernel)
__global__ __launch_bounds__(256) void fc1_reduce_kernel(
    const float* __restrict__ partial, const float* __restrict__ bias,
    float* __restrict__ h1) {
  const int g = threadIdx.x >> 5, il = threadIdx.x & 31;
  const int idx = blockIdx.x * 32 + il;
  const float* p = partial + (size_t)g * 15360 + idx;
  float s = 0.f;
#pragma unroll 8
  for (int q = 0; q < 64; q++) s += p[(size_t)(q * 8) * 15360];
  __shared__ float red[8][32];
  red[g][il] = s;
  __syncthreads();
  if (threadIdx.x < 32) {
    float tsum = 0.f;
#pragma unroll
    for (int gg = 0; gg < 8; gg++) tsum += red[gg][threadIdx.x];
    h1[idx] = fmaxf(tsum + bias[idx % 120], 0.f);
  }
}

// ---------------- Kernel 5: fc2 + fc3 + RBF + sigmoid ----------------------
__global__ __launch_bounds__(128) void head_kernel(
    const float* __restrict__ h1, const float* __restrict__ fc2_w,
    const float* __restrict__ fc2_b, const float* __restrict__ fc3_w,
    const float* __restrict__ fc3_b, const float* __restrict__ support,
    float* __restrict__ out) {
  int b = blockIdx.x, t = threadIdx.x;
  __shared__ float hrow[120];
  __shared__ float s2[84];
  if (t < 120) hrow[t] = h1[b * 120 + t];
  __syncthreads();
  if (t < 84) {
    float d = fc2_b[t];
    for (int k = 0; k < 120; k++) d += fc2_w[t * 120 + k] * hrow[k];
    s2[t] = fmaxf(d, 0.f);
  }
  __syncthreads();
  if (t == 0) {
    float h = fc3_b[0];
    for (int j = 0; j < 84; j++) h += fc3_w[j] * s2[j];
    float ks = 0.f;
    for (int j = 0; j < 10; j++) {
      float diff = h - support[j];
      ks += expf(-diff * diff);
    }
    ks *= 0.1f;
    float p = 1.f / (1.f + expf(-ks));
    out[b * 2] = p;
    out[b * 2 + 1] = 1.f - p;
  }
}

// ---------------------------------------------------------------------------
extern "C" void kernel_launch(void* const* d_in, const int* in_sizes, int n_in,
                              void* d_out, int out_size, void* d_ws, size_t ws_size,
                              hipStream_t stream) {
  const float* x   = (const float*)d_in[0];
  const float* c1w = (const float*)d_in[1];
  const float* c1b = (const float*)d_in[2];
  const float* c2w = (const float*)d_in[3];
  const float* c2b = (const float*)d_in[4];
  const float* f1w = (const float*)d_in[5];
  const float* f1b = (const float*)d_in[6];
  const float* f2w = (const float*)d_in[7];
  const float* f2b = (const float*)d_in[8];
  const float* f3w = (const float*)d_in[9];
  const float* f3b = (const float*)d_in[10];
  const float* sup = (const float*)d_in[11];
  float* out = (float*)d_out;

  char* ws = (char*)d_ws;
  // Lifetimes: pool1 [0,46.5MB) dead after conv2 -> part/h1 reuse it.
  float* pool1 = (float*)ws;                     // 46,476,288 B
  float* act   = (float*)(ws + 46476288);        // 128*KPAD*4 = 28,577,792 B
  float* part  = (float*)ws;                     // 512*15360*4 = 31,457,280 B
  float* h1    = (float*)(ws + 33000000);        //     61,440 B

  conv1_pool_kernel<<<dim3(4, 18, BATCH), 64, 0, stream>>>(x, c1w, c1b, pool1);
  conv2_pool_kernel<<<dim3(2, 4, BATCH), 256, 0, stream>>>(pool1, c2w, c2b, act);
  fc1_splitk_kernel<<<NPART, 512, 0, stream>>>(act, f1w, part);
  fc1_reduce_kernel<<<480, 256, 0, stream>>>(part, f1b, h1);
  head_kernel<<<BATCH, 128, 0, stream>>>(h1, f2w, f2b, f3w, f3b, sup, out);
}